// Round 1
// 263.816 us; speedup vs baseline: 1.0528x; 1.0528x over previous
//
#include <hip/hip_runtime.h>

#define N_ATOMS 4096
#define T_TOK   512
#define TOKEN_S 384
#define TOKEN_Z 128

using bfrag = __attribute__((ext_vector_type(8))) short;   // 8 bf16 (4 VGPRs)
using f4    = __attribute__((ext_vector_type(4))) float;

__device__ __forceinline__ short f2bf(float f) {
    unsigned u = __float_as_uint(f);
    unsigned r = u + 0x7FFFu + ((u >> 16) & 1u);   // RNE
    return (short)(r >> 16);
}
__device__ __forceinline__ float bf2f(unsigned short s) {
    return __uint_as_float(((unsigned)s) << 16);
}

// ---------------------------------------------------------------------------
// setup_kernel: tok extraction + weight-frag prep + reductions.
// blocks 0..50   : bf16 B-frag builders (zpW/featW/WcqF/WckF/s2cW)
// block 51       : bias16 / cs16
// block 52       : cs128 / bs128
// blocks 53..1076: tok from one-hot a2t (one wave per atom)
// ---------------------------------------------------------------------------
__global__ __launch_bounds__(256) void setup_kernel(
    const float* __restrict__ a2t, const float* __restrict__ Wz,
    const float* __restrict__ gz, const float* __restrict__ bz,
    const float* __restrict__ Wf, const float* __restrict__ Wcq,
    const float* __restrict__ Wck, const float* __restrict__ Ws2c,
    const float* __restrict__ gs, const float* __restrict__ bs,
    int* __restrict__ tok, short* __restrict__ zpW,
    short* __restrict__ featW, short* __restrict__ WcqF,
    short* __restrict__ WckF, short* __restrict__ s2cW,
    float* __restrict__ bias16, float* __restrict__ cs16,
    float* __restrict__ cs128, float* __restrict__ bs128) {
    const int b = blockIdx.x, tid = threadIdx.x;
    if (b >= 53) {                      // tok
        const int wave = tid >> 6, lane = tid & 63;
        const int n = (b - 53) * 4 + wave;
        const float* row = a2t + (size_t)n * T_TOK;
        int found = 0;
#pragma unroll
        for (int m = 0; m < T_TOK / 64; ++m)
            if (row[lane + 64 * m] > 0.5f) found = lane + 64 * m;
#pragma unroll
        for (int off = 32; off >= 1; off >>= 1)
            found = max(found, __shfl_xor(found, off, 64));
        if (lane == 0) tok[n] = found;
        return;
    }
    if (b == 51) {                      // bias16 / cs16
        const int o = tid >> 3, s = tid & 7;
        const float* vec = (o < 16) ? bz : gz;
        const int n = o & 15;
        float p = 0.f;
#pragma unroll
        for (int i = 0; i < 16; ++i) {
            const int k = s + 8 * i;
            p += vec[k] * Wz[k * 16 + n];
        }
        p += __shfl_xor(p, 1, 64); p += __shfl_xor(p, 2, 64);
        p += __shfl_xor(p, 4, 64);
        if (s == 0) { if (o < 16) bias16[n] = p; else cs16[n] = p; }
        return;
    }
    if (b == 52) {                      // cs128 / bs128
        const int o = tid & 127, arr = tid >> 7;
        const float* vec = arr ? bs : gs;
        float s = 0.f;
        for (int k = 0; k < TOKEN_S; ++k)
            s += vec[k] * Ws2c[(size_t)k * 128 + o];
        if (arr) bs128[o] = s; else cs128[o] = s;
        return;
    }
    // frag builders
    const int id = b * 256 + tid;
    const int lane = id & 63, fs = id >> 6;
    const int quad = lane >> 4, n = lane & 15;
    short v[8];
    short* dst;
    if (fs < 4) {                       // zp weights: g*Wz
#pragma unroll
        for (int j = 0; j < 8; ++j) {
            int k = fs * 32 + quad * 8 + j;
            v[j] = f2bf(gz[k] * Wz[k * 16 + n]);
        }
        dst = zpW + (size_t)(fs * 64 + lane) * 8;
    } else if (fs < 100) {              // feat weights rows 4..387
        const int idx = fs - 4, kb = idx >> 3, nt = idx & 7;
#pragma unroll
        for (int j = 0; j < 8; ++j) {
            int f = 4 + kb * 32 + quad * 8 + j;
            v[j] = f2bf(Wf[(size_t)f * 128 + nt * 16 + n]);
        }
        dst = featW + (size_t)(idx * 64 + lane) * 8;
    } else if (fs < 104) {              // W_cq
        const int kb = fs - 100;
#pragma unroll
        for (int j = 0; j < 8; ++j) {
            int k = kb * 32 + quad * 8 + j;
            v[j] = f2bf(Wcq[k * 16 + n]);
        }
        dst = WcqF + (size_t)(kb * 64 + lane) * 8;
    } else if (fs < 108) {              // W_ck
        const int kb = fs - 104;
#pragma unroll
        for (int j = 0; j < 8; ++j) {
            int k = kb * 32 + quad * 8 + j;
            v[j] = f2bf(Wck[k * 16 + n]);
        }
        dst = WckF + (size_t)(kb * 64 + lane) * 8;
    } else {                            // s2c weights: gs*Ws2c
        const int idx = fs - 108, kb = idx >> 3, nt = idx & 7;
#pragma unroll
        for (int j = 0; j < 8; ++j) {
            int k = kb * 32 + quad * 8 + j;
            v[j] = f2bf(gs[k] * Ws2c[(size_t)k * 128 + nt * 16 + n]);
        }
        dst = s2cW + (size_t)(idx * 64 + lane) * 8;
    }
#pragma unroll
    for (int j = 0; j < 8; ++j) dst[j] = v[j];
}

// ---------------------------------------------------------------------------
// s2c_band_kernel: 33 blocks x 512.
//  blocks 0..31 : s2c = LN(s_trunk) @ W_s2c via MFMA (8 waves = 8 nt blocks)
//  block 32     : band (LDS atomics) + worklist scan, all in one block.
// Fuses 3 former dispatches; band/worklist runs concurrently with s2c.
// ---------------------------------------------------------------------------
__global__ __launch_bounds__(512) void s2c_band_kernel(
    const float* __restrict__ s_trunk, const short* __restrict__ s2cW,
    const float* __restrict__ cs128, const float* __restrict__ bs128,
    const int* __restrict__ tok, float* __restrict__ s2c,
    int* __restrict__ wl, int* __restrict__ wl_count) {
    __shared__ int sh_lo[512], sh_hi[512], scan[512];
    const int b = blockIdx.x;
    if (b == 32) {                      // band + worklist
        const int t = threadIdx.x;
        sh_lo[t] = 0x7FFFFFFF; sh_hi[t] = -1;
        __syncthreads();
#pragma unroll
        for (int i = 0; i < 8; ++i) {
            const int a = t * 8 + i;
            const int tt = tok[a];
            int am = a - 79; if (am < 0) am = 0;
            int ap = a + 79; if (ap > N_ATOMS - 1) ap = N_ATOMS - 1;
            atomicMin(&sh_lo[tt], tok[am]);
            atomicMax(&sh_hi[tt], tok[ap]);
        }
        __syncthreads();
        const int l = sh_lo[t], h = sh_hi[t];
        const int n = (h >= l) ? ((h - l) >> 4) + 1 : 0;
        scan[t] = n;
        __syncthreads();
        for (int off = 1; off < 512; off <<= 1) {
            int add = (t >= off) ? scan[t - off] : 0;
            __syncthreads();
            scan[t] += add;
            __syncthreads();
        }
        const int off0 = scan[t] - n;
        for (int i = 0; i < n; ++i) {
            int tk0 = l + i * 16;
            if (tk0 > T_TOK - 16) tk0 = T_TOK - 16;
            wl[off0 + i] = (t << 16) | tk0;
        }
        if (t == 511) *wl_count = scan[511];
        return;
    }
    // s2c tile b, wave = nt
    const int wave = threadIdx.x >> 6, lane = threadIdx.x & 63;
    const int m = lane & 15, quad = lane >> 4;
    const int nt = wave;
    const int t0 = b * 16;
    const float* xrow = s_trunk + (size_t)(t0 + m) * TOKEN_S;

    bfrag A[12];
    float xs = 0.f, xq = 0.f;
#pragma unroll
    for (int kb = 0; kb < 12; ++kb) {
        const float4* p = (const float4*)(xrow + kb * 32 + quad * 8);
        float4 x0 = p[0], x1 = p[1];
        const float xv[8] = {x0.x, x0.y, x0.z, x0.w, x1.x, x1.y, x1.z, x1.w};
#pragma unroll
        for (int j = 0; j < 8; ++j) {
            A[kb][j] = f2bf(xv[j]);
            xs += xv[j]; xq = fmaf(xv[j], xv[j], xq);
        }
    }
    xs += __shfl_xor(xs, 16, 64); xs += __shfl_xor(xs, 32, 64);
    xq += __shfl_xor(xq, 16, 64); xq += __shfl_xor(xq, 32, 64);
    const float mean = xs * (1.f / TOKEN_S);
    const float var  = xq * (1.f / TOKEN_S) - mean * mean;
    const float rstd = rsqrtf(var + 1e-5f);
    const float mrs  = mean * rstd;

    const bfrag* Bb = (const bfrag*)s2cW;
    f4 acc = {0.f, 0.f, 0.f, 0.f};
#pragma unroll
    for (int kb = 0; kb < 12; ++kb)
        acc = __builtin_amdgcn_mfma_f32_16x16x32_bf16(
            A[kb], Bb[(kb * 8 + nt) * 64 + lane], acc, 0, 0, 0);

    const int cn = nt * 16 + m;
    const float csn = cs128[cn], bsn = bs128[cn];
#pragma unroll
    for (int reg = 0; reg < 4; ++reg) {
        const int r = quad * 4 + reg;
        const float rs = __shfl(rstd, r, 64);
        const float ms = __shfl(mrs, r, 64);
        s2c[(size_t)(t0 + r) * 128 + cn] = rs * acc[reg] - ms * csn + bsn;
    }
}

// ---------------------------------------------------------------------------
// zp_feat_kernel: 640 blocks x 256.
//  blocks 0..511  : zp over worklist tiles (persistent, wave-per-tile)
//  blocks 512..639: featcatk, 32 atoms per block (4 waves = 2 sub-groups)
// The two stages are independent (both need only K1+K2 outputs); fusing them
// lets idle zp waves' CUs pick up featcatk blocks immediately.
// ---------------------------------------------------------------------------
__global__ __launch_bounds__(256) void zp_feat_kernel(
    const float* __restrict__ z, const short* __restrict__ zpW,
    const float* __restrict__ bias16, const float* __restrict__ cs16,
    const int* __restrict__ wl, const int* __restrict__ wl_count,
    unsigned short* __restrict__ zp_bf,
    const float* __restrict__ pos, const float* __restrict__ charge,
    const float* __restrict__ elem, const float* __restrict__ namec,
    const float* __restrict__ Wf, const float* __restrict__ bf,
    const float* __restrict__ s2c, const int* __restrict__ tok,
    const short* __restrict__ featW, const short* __restrict__ WcqF,
    const short* __restrict__ WckF, float* __restrict__ q_out,
    float* __restrict__ c_out, float* __restrict__ acq,
    float* __restrict__ ack) {
    __shared__ short ctile[32 * 136];
    const int wave = threadIdx.x >> 6, lane = threadIdx.x & 63;
    const int m = lane & 15, quad = lane >> 4;

    if (blockIdx.x < 512) {             // ---- zp ----
        const int count = *wl_count;
        const bfrag* wb = (const bfrag*)zpW;
        const float csn = cs16[m], bn = bias16[m];

        for (int idx = blockIdx.x * 4 + wave; idx < count; idx += 2048) {
            const int e = wl[idx];
            const int tq = e >> 16, tk0 = e & 0xFFFF;
            const size_t r0 = (size_t)tq * T_TOK + tk0;
            const float* zrow = z + (r0 + m) * (size_t)TOKEN_Z;

            bfrag A[4];
            float xs = 0.f, xq = 0.f;
#pragma unroll
            for (int kb = 0; kb < 4; ++kb) {
                const float4* p = (const float4*)(zrow + kb * 32 + quad * 8);
                float4 x0 = p[0], x1 = p[1];
                const float xv[8] = {x0.x, x0.y, x0.z, x0.w,
                                     x1.x, x1.y, x1.z, x1.w};
#pragma unroll
                for (int j = 0; j < 8; ++j) {
                    A[kb][j] = f2bf(xv[j]);
                    xs += xv[j]; xq = fmaf(xv[j], xv[j], xq);
                }
            }
            xs += __shfl_xor(xs, 16, 64); xs += __shfl_xor(xs, 32, 64);
            xq += __shfl_xor(xq, 16, 64); xq += __shfl_xor(xq, 32, 64);
            const float mean = xs * (1.f / TOKEN_Z);
            const float var  = xq * (1.f / TOKEN_Z) - mean * mean;
            const float rstd = rsqrtf(var + 1e-5f);
            const float mrs  = mean * rstd;

            f4 acc = {0.f, 0.f, 0.f, 0.f};
#pragma unroll
            for (int kb = 0; kb < 4; ++kb)
                acc = __builtin_amdgcn_mfma_f32_16x16x32_bf16(
                    A[kb], wb[kb * 64 + lane], acc, 0, 0, 0);
#pragma unroll
            for (int reg = 0; reg < 4; ++reg) {
                const int r = quad * 4 + reg;
                const float rs = __shfl(rstd, r, 64);
                const float ms = __shfl(mrs, r, 64);
                zp_bf[(r0 + r) * 16 + m] =
                    (unsigned short)f2bf(rs * acc[reg] - ms * csn + bn);
            }
        }
        return;
    }

    // ---- featcatk: 32 atoms, waves {0,1}->atoms a0..a0+15, {2,3}->+16..31 --
    const int sub = wave >> 1, w2 = wave & 1;
    const int a0 = (blockIdx.x - 512) * 32 + sub * 16;
    const int ntb = w2 * 4;

    f4 acc[4];
#pragma unroll
    for (int nt = 0; nt < 4; ++nt) acc[nt] = (f4){0.f, 0.f, 0.f, 0.f};
    const bfrag* Bb = (const bfrag*)featW;
#pragma unroll
    for (int kb = 0; kb < 12; ++kb) {
        const int f0 = kb * 32 + quad * 8;
        const float* src = (kb < 4)
            ? (elem + (size_t)(a0 + m) * 128 + f0)
            : (namec + (size_t)(a0 + m) * 256 + f0 - 128);
        float4 x0 = ((const float4*)src)[0];
        float4 x1 = ((const float4*)src)[1];
        bfrag A;
        A[0] = f2bf(x0.x); A[1] = f2bf(x0.y); A[2] = f2bf(x0.z); A[3] = f2bf(x0.w);
        A[4] = f2bf(x1.x); A[5] = f2bf(x1.y); A[6] = f2bf(x1.z); A[7] = f2bf(x1.w);
#pragma unroll
        for (int nt = 0; nt < 4; ++nt)
            acc[nt] = __builtin_amdgcn_mfma_f32_16x16x32_bf16(
                A, Bb[(kb * 8 + ntb + nt) * 64 + lane], acc[nt], 0, 0, 0);
    }
    float px[4], py[4], pz[4], ch[4];
    int tk4[4];
#pragma unroll
    for (int reg = 0; reg < 4; ++reg) {
        const int a = a0 + quad * 4 + reg;
        px[reg] = pos[a * 3 + 0]; py[reg] = pos[a * 3 + 1];
        pz[reg] = pos[a * 3 + 2]; ch[reg] = charge[a];
        tk4[reg] = tok[a];
    }
#pragma unroll
    for (int nt = 0; nt < 4; ++nt) {
        const int cn = (ntb + nt) * 16 + m;
        const float w0 = Wf[cn], w1 = Wf[128 + cn], w2f = Wf[256 + cn],
                    w3 = Wf[384 + cn], bv = bf[cn];
#pragma unroll
        for (int reg = 0; reg < 4; ++reg) {
            const int r = quad * 4 + reg;
            float qv = acc[nt][reg] + px[reg] * w0 + py[reg] * w1 +
                       pz[reg] * w2f + ch[reg] * w3 + bv;
            q_out[(size_t)(a0 + r) * 128 + cn] = qv;
            float cv = qv + s2c[(size_t)tk4[reg] * 128 + cn];
            c_out[(size_t)(a0 + r) * 128 + cn] = cv;
            ctile[(sub * 16 + r) * 136 + cn] = f2bf(fmaxf(cv, 0.f));
        }
    }
    __syncthreads();
    const bfrag* BW = w2 ? (const bfrag*)WckF : (const bfrag*)WcqF;
    float* dst = w2 ? ack : acq;
    f4 a2 = {0.f, 0.f, 0.f, 0.f};
#pragma unroll
    for (int kb = 0; kb < 4; ++kb) {
        bfrag Af = *(const bfrag*)&ctile[(sub * 16 + m) * 136 + kb * 32 + quad * 8];
        a2 = __builtin_amdgcn_mfma_f32_16x16x32_bf16(Af, BW[kb * 64 + lane],
                                                     a2, 0, 0, 0);
    }
#pragma unroll
    for (int reg = 0; reg < 4; ++reg)
        dst[(size_t)(a0 + quad * 4 + reg) * 16 + m] = a2[reg];
}

// ---------------------------------------------------------------------------
// pair tensor via LDS-free MFMA MLP chain (zp input bf16).
// ---------------------------------------------------------------------------
__global__ __launch_bounds__(256) void pair_mfma_kernel(
    const float* __restrict__ pos, const int* __restrict__ uid,
    const int* __restrict__ tok, const unsigned short* __restrict__ zp_bf,
    const float* __restrict__ acq, const float* __restrict__ ack,
    const float* __restrict__ W_pos, const float* __restrict__ W_dist,
    const float* __restrict__ W_mask, const float* __restrict__ W_m1,
    const float* __restrict__ W_m2, const float* __restrict__ W_m3,
    float* __restrict__ p_out) {
    const int wave = threadIdx.x >> 6, lane = threadIdx.x & 63;
    const int m = lane & 15, quad = lane >> 4;
    const int qa = blockIdx.x * 4 + wave;
    const int j = qa >> 5;

    bfrag A1, A2, A3;
#pragma unroll
    for (int jj = 0; jj < 4; ++jj) {
        const int d = quad * 4 + jj;
        A1[jj] = f2bf(W_m1[d * 16 + m]); A1[jj + 4] = 0;
        A2[jj] = f2bf(W_m2[d * 16 + m]); A2[jj + 4] = 0;
        A3[jj] = f2bf(W_m3[d * 16 + m]); A3[jj + 4] = 0;
    }
    float wp0[4], wp1[4], wp2[4], wd[4], wm[4];
#pragma unroll
    for (int jj = 0; jj < 4; ++jj) {
        const int d = quad * 4 + jj;
        wp0[jj] = W_pos[d]; wp1[jj] = W_pos[16 + d]; wp2[jj] = W_pos[32 + d];
        wd[jj] = W_dist[d]; wm[jj] = W_mask[d];
    }
    const float pqx = pos[qa * 3 + 0], pqy = pos[qa * 3 + 1],
                pqz = pos[qa * 3 + 2];
    const int uq = uid[qa], tq = tok[qa];
    const float4 aq = *(const float4*)(acq + (size_t)qa * 16 + quad * 4);
    const float aqv[4] = {aq.x, aq.y, aq.z, aq.w};
    float* pbase = p_out + (size_t)qa * 2048;

    const f4 zero = {0.f, 0.f, 0.f, 0.f};
#pragma unroll
    for (int g = 0; g < 8; ++g) {
        const int kk = g * 16 + m;
        const int src = j * 32 + kk - 48;
        const bool valid = ((unsigned)src < (unsigned)N_ATOMS);
        float dx = 0.f, dy = 0.f, dz = 0.f, dn = 0.f, vflag = 0.f;
        float zv[4] = {0.f, 0.f, 0.f, 0.f}, av[4] = {0.f, 0.f, 0.f, 0.f};
        if (valid) {
            dx = pos[src * 3 + 0] - pqx;
            dy = pos[src * 3 + 1] - pqy;
            dz = pos[src * 3 + 2] - pqz;
            dn = 1.f / (1.f + dx * dx + dy * dy + dz * dz);
            vflag = (uid[src] == uq) ? 1.f : 0.f;
            const int tk_ = tok[src];
            ushort4 zl = *(const ushort4*)(zp_bf +
                            ((size_t)tq * T_TOK + tk_) * 16 + quad * 4);
            float4 al = *(const float4*)(ack + (size_t)src * 16 + quad * 4);
            zv[0] = bf2f(zl.x); zv[1] = bf2f(zl.y);
            zv[2] = bf2f(zl.z); zv[3] = bf2f(zl.w);
            av[0] = al.x; av[1] = al.y; av[2] = al.z; av[3] = al.w;
        }
        float pb[4];
        bfrag B;
#pragma unroll
        for (int jj = 0; jj < 4; ++jj) {
            float t = dx * wp0[jj] + dy * wp1[jj] + dz * wp2[jj] +
                      dn * wd[jj] + wm[jj];
            pb[jj] = vflag * t + zv[jj] + av[jj] + aqv[jj];
            B[jj] = f2bf(fmaxf(pb[jj], 0.f));
            B[jj + 4] = 0;
        }
        f4 t1 = __builtin_amdgcn_mfma_f32_16x16x32_bf16(A1, B, zero, 0, 0, 0);
        bfrag B2;
#pragma unroll
        for (int jj = 0; jj < 4; ++jj) {
            B2[jj] = f2bf(fmaxf(t1[jj], 0.f)); B2[jj + 4] = 0;
        }
        f4 t2 = __builtin_amdgcn_mfma_f32_16x16x32_bf16(A2, B2, zero, 0, 0, 0);
        bfrag B3;
#pragma unroll
        for (int jj = 0; jj < 4; ++jj) {
            B3[jj] = f2bf(fmaxf(t2[jj], 0.f)); B3[jj + 4] = 0;
        }
        f4 t3 = __builtin_amdgcn_mfma_f32_16x16x32_bf16(A3, B3, zero, 0, 0, 0);
        float4 o = make_float4(pb[0] + t3[0], pb[1] + t3[1],
                               pb[2] + t3[2], pb[3] + t3[3]);
        *(float4*)(pbase + kk * 16 + quad * 4) = o;
    }
}

// ---------------------------------------------------------------------------
extern "C" void kernel_launch(void* const* d_in, const int* in_sizes, int n_in,
                              void* d_out, int out_size, void* d_ws, size_t ws_size,
                              hipStream_t stream) {
    const float* ref_pos     = (const float*)d_in[0];
    const float* ref_charge  = (const float*)d_in[1];
    const float* ref_element = (const float*)d_in[2];
    const float* ref_name    = (const float*)d_in[3];
    const int*   uid         = (const int*)d_in[5];
    const float* a2t         = (const float*)d_in[6];
    const float* s_trunk     = (const float*)d_in[7];
    const float* z           = (const float*)d_in[8];
    const float* W_feat      = (const float*)d_in[9];
    const float* b_feat      = (const float*)d_in[10];
    const float* W_pos       = (const float*)d_in[11];
    const float* W_dist      = (const float*)d_in[12];
    const float* W_mask      = (const float*)d_in[13];
    const float* ln_s_g      = (const float*)d_in[14];
    const float* ln_s_b      = (const float*)d_in[15];
    const float* W_s2c       = (const float*)d_in[16];
    const float* ln_z_g      = (const float*)d_in[17];
    const float* ln_z_b      = (const float*)d_in[18];
    const float* W_z2p       = (const float*)d_in[19];
    const float* W_cq        = (const float*)d_in[20];
    const float* W_ck        = (const float*)d_in[21];
    const float* W_m1        = (const float*)d_in[22];
    const float* W_m2        = (const float*)d_in[23];
    const float* W_m3        = (const float*)d_in[24];

    float* out = (float*)d_out;
    float* q_out = out;                        // 4096*128
    float* c_out = out + 524288;               // 4096*128
    float* p_out = out + 1048576;              // 128*32*128*16

    char* w = (char*)d_ws;
    unsigned short* zp_bf = (unsigned short*)w;      // 4194304 bf16 (8 MB)
    float* s2c  = (float*)(w + 8388608);             // 65536 f32
    float* acq  = s2c + 65536;                       // 65536
    float* ack  = acq + 65536;                       // 65536
    int*   tok  = (int*)(ack + 65536);               // 4096
    short* zpW   = (short*)(tok + 4096);             // 2048
    short* featW = zpW + 2048;                       // 49152
    short* WcqF  = featW + 49152;                    // 2048
    short* WckF  = WcqF + 2048;                      // 2048
    short* s2cW  = WckF + 2048;                      // 49152
    float* bias16 = (float*)(s2cW + 49152);          // 16
    float* cs16   = bias16 + 16;                     // 16
    float* cs128  = cs16 + 16;                       // 128
    float* bs128  = cs128 + 128;                     // 128
    int*   wl     = (int*)(bs128 + 128);             // 16384+64
    int*   wl_cnt = wl + 16448;                      // 1

    setup_kernel<<<1077, 256, 0, stream>>>(a2t, W_z2p, ln_z_g, ln_z_b,
                                           W_feat, W_cq, W_ck, W_s2c,
                                           ln_s_g, ln_s_b, tok, zpW, featW,
                                           WcqF, WckF, s2cW, bias16, cs16,
                                           cs128, bs128);
    s2c_band_kernel<<<33, 512, 0, stream>>>(s_trunk, s2cW, cs128, bs128,
                                            tok, s2c, wl, wl_cnt);
    zp_feat_kernel<<<640, 256, 0, stream>>>(z, zpW, bias16, cs16, wl, wl_cnt,
                                            zp_bf,
                                            ref_pos, ref_charge, ref_element,
                                            ref_name, W_feat, b_feat, s2c, tok,
                                            featW, WcqF, WckF,
                                            q_out, c_out, acq, ack);
    pair_mfma_kernel<<<1024, 256, 0, stream>>>(ref_pos, uid, tok, zp_bf,
                                               acq, ack, W_pos, W_dist, W_mask,
                                               W_m1, W_m2, W_m3, p_out);
}